// Round 2
// baseline (338.173 us; speedup 1.0000x reference)
//
#include <hip/hip_runtime.h>
#include <hip/hip_bf16.h>

#define T_DIM 32772
#define NGROUP 2048

typedef short short8v __attribute__((ext_vector_type(8)));
typedef float float4v __attribute__((ext_vector_type(4)));
typedef unsigned int uint4v __attribute__((ext_vector_type(4)));

// packed f32x2 -> bf16x2 (RTNE) -> u32; compiler emits v_cvt_pk_bf16_f32
__device__ __forceinline__ unsigned int f2bf2(float a, float b) {
    __hip_bfloat162 h = __float22bfloat162_rn(make_float2(a, b));
    union { __hip_bfloat162 h; unsigned int u; } c; c.h = h;
    return c.u;
}

__device__ __forceinline__ short8v pack8(const float4v u0, const float4v u1) {
    uint4v p;
    p[0] = f2bf2(u0[0], u0[1]);
    p[1] = f2bf2(u0[2], u0[3]);
    p[2] = f2bf2(u1[0], u1[1]);
    p[3] = f2bf2(u1[2], u1[3]);
    return __builtin_bit_cast(short8v, p);
}

// One block per chamfer group g (B*H = 2048), 8 waves.
// x = targ obs (n, 256x128) held as per-wave register A-frags.
// y = preds obs (m, 256x128) read per col-tile directly from global (L1/L2 reuse).
// P = x2[n] + y2[m] - 2*x.y ; loss1 = sum_m min_n P ; loss2 = sum_n min_m P
__global__ __launch_bounds__(512) void chamfer_kernel(
    const float* __restrict__ preds, const float* __restrict__ targ,
    float* __restrict__ ch_out)
{
    __shared__ float y2s[256];
    __shared__ float colmin_w[8][256];
    __shared__ float redA[8];
    __shared__ float redB[4];

    const int g = blockIdx.x;
    const float* gx = targ  + (size_t)g * T_DIM + 4;
    const float* gy = preds + (size_t)g * T_DIM + 4;

    const int tid  = threadIdx.x;
    const int lane = tid & 63;
    const int w    = tid >> 6;   // wave 0..7, owns x rows [32w, 32w+32)
    const int lg   = lane >> 4;  // lane group 0..3 (k-quarter)
    const int lc   = lane & 15;  // row/col within 16-tile

    // ---- A fragments + x2, registers only (no LDS, no barrier) ----
    short8v a_frag[2][4];
    float x2r[2][4];
    #pragma unroll
    for (int ti = 0; ti < 2; ++ti) {
        const float* xr = gx + (size_t)(w * 32 + ti * 16 + lc) * 128;
        float ss = 0.f;
        #pragma unroll
        for (int kk = 0; kk < 4; ++kk) {
            const float4v u0 = *reinterpret_cast<const float4v*>(xr + kk * 32 + lg * 8);
            const float4v u1 = *reinterpret_cast<const float4v*>(xr + kk * 32 + lg * 8 + 4);
            ss += u0[0]*u0[0] + u0[1]*u0[1] + u0[2]*u0[2] + u0[3]*u0[3];
            ss += u1[0]*u1[0] + u1[1]*u1[1] + u1[2]*u1[2] + u1[3]*u1[3];
            a_frag[ti][kk] = pack8(u0, u1);
        }
        // combine the 4 k-quarters -> full row norm (all lanes of same lc agree)
        ss += __shfl_xor(ss, 16);
        ss += __shfl_xor(ss, 32);
        // redistribute: lane (lc,lg) needs x2 of rows ti*16 + lg*4 + r
        #pragma unroll
        for (int r = 0; r < 4; ++r)
            x2r[ti][r] = __shfl(ss, lg * 4 + r);
    }

    // ---- y2 cooperative pass (also warms L2 with y); the ONLY staging barrier ----
    {
        const int row = tid >> 1;
        const int hf  = tid & 1;
        const float* yr = gy + (size_t)row * 128 + hf * 64;
        float ss = 0.f;
        #pragma unroll
        for (int i = 0; i < 16; ++i) {
            const float4v u = *reinterpret_cast<const float4v*>(yr + i * 4);
            ss += u[0]*u[0] + u[1]*u[1] + u[2]*u[2] + u[3]*u[3];
        }
        ss += __shfl_xor(ss, 1);
        if (hf == 0) y2s[row] = ss;
    }
    __syncthreads();

    float rowmin[2][4];
    #pragma unroll
    for (int ti = 0; ti < 2; ++ti)
        #pragma unroll
        for (int r = 0; r < 4; ++r) rowmin[ti][r] = 1e30f;

    // ---- 16 col-tiles; B-frags straight from global; zero barriers ----
    #pragma unroll 1
    for (int tj = 0; tj < 16; ++tj) {
        const float* yb = gy + (size_t)(tj * 16 + lc) * 128;
        float4v u[8];
        #pragma unroll
        for (int kk = 0; kk < 4; ++kk) {
            u[2*kk]   = *reinterpret_cast<const float4v*>(yb + kk * 32 + lg * 8);
            u[2*kk+1] = *reinterpret_cast<const float4v*>(yb + kk * 32 + lg * 8 + 4);
        }
        short8v b_frag[4];
        #pragma unroll
        for (int kk = 0; kk < 4; ++kk)
            b_frag[kk] = pack8(u[2*kk], u[2*kk+1]);

        const float y2c = y2s[tj * 16 + lc];
        float cminv = 1e30f;
        #pragma unroll
        for (int ti = 0; ti < 2; ++ti) {
            float4v acc = {0.f, 0.f, 0.f, 0.f};
            #pragma unroll
            for (int kk = 0; kk < 4; ++kk)
                acc = __builtin_amdgcn_mfma_f32_16x16x32_bf16(
                    a_frag[ti][kk], b_frag[kk], acc, 0, 0, 0);
            #pragma unroll
            for (int r = 0; r < 4; ++r) {
                const float P = (x2r[ti][r] + y2c) - 2.0f * acc[r];
                rowmin[ti][r] = fminf(rowmin[ti][r], P);
                cminv = fminf(cminv, P);
            }
        }
        // col-min over this wave's 32 rows (combine the 4 lane groups)
        cminv = fminf(cminv, __shfl_xor(cminv, 16));
        cminv = fminf(cminv, __shfl_xor(cminv, 32));
        if (lg == 0) colmin_w[w][tj * 16 + lc] = cminv;
    }

    // ---- loss2: row-mins (min over lc lanes, sum over rows) ----
    float s2 = 0.f;
    #pragma unroll
    for (int ti = 0; ti < 2; ++ti)
        #pragma unroll
        for (int r = 0; r < 4; ++r) {
            float v = rowmin[ti][r];
            v = fminf(v, __shfl_xor(v, 1));
            v = fminf(v, __shfl_xor(v, 2));
            v = fminf(v, __shfl_xor(v, 4));
            v = fminf(v, __shfl_xor(v, 8));
            s2 += v;
        }
    s2 += __shfl_xor(s2, 16);
    s2 += __shfl_xor(s2, 32);
    if (lane == 0) redA[w] = s2;
    __syncthreads();

    // ---- loss1: min over 8 waves per col, sum over 256 cols ----
    if (tid < 256) {
        float m = colmin_w[0][tid];
        #pragma unroll
        for (int ww = 1; ww < 8; ++ww) m = fminf(m, colmin_w[ww][tid]);
        #pragma unroll
        for (int s = 1; s < 64; s <<= 1) m += __shfl_xor(m, s);
        if (lane == 0) redB[w] = m;
    }
    __syncthreads();
    if (tid == 0) {
        const float l1 = redB[0] + redB[1] + redB[2] + redB[3];
        float l2 = 0.f;
        #pragma unroll
        for (int ww = 0; ww < 8; ++ww) l2 += redA[ww];
        ch_out[g] = l1 + l2;
    }
}

// Action loss + final reduction -> out[0], out[1]
__global__ __launch_bounds__(256) void final_kernel(
    const float* __restrict__ preds, const float* __restrict__ targ,
    const float* __restrict__ ch, float* __restrict__ out)
{
    __shared__ float rsw[4], rsa[4], rsc[4];
    const int tid = threadIdx.x;
    const int lane = tid & 63, w = tid >> 6;
    float sw = 0.f, sa0 = 0.f, sc = 0.f;
    for (int p = tid; p < NGROUP; p += 256) {
        const float* pp = preds + (size_t)p * T_DIM;
        const float* tt = targ  + (size_t)p * T_DIM;
        float al = 0.f;
        #pragma unroll
        for (int d = 0; d < 4; ++d) { const float df = pp[d] - tt[d]; al += df * df; }
        al *= 0.25f;
        if ((p & 31) == 0) { sw += 10.f * al; sa0 += al; }
        else               { sw += al; }
        sc += ch[p];
    }
    #pragma unroll
    for (int s = 1; s < 64; s <<= 1) {
        sw  += __shfl_xor(sw, s);
        sa0 += __shfl_xor(sa0, s);
        sc  += __shfl_xor(sc, s);
    }
    if (lane == 0) { rsw[w] = sw; rsa[w] = sa0; rsc[w] = sc; }
    __syncthreads();
    if (tid == 0) {
        float tsw = 0.f, tsa = 0.f, tsc = 0.f;
        #pragma unroll
        for (int i = 0; i < 4; ++i) { tsw += rsw[i]; tsa += rsa[i]; tsc += rsc[i]; }
        out[0] = tsw / 2048.f + tsc / 2048.f;
        out[1] = tsa / 64.f;
    }
}

extern "C" void kernel_launch(void* const* d_in, const int* in_sizes, int n_in,
                              void* d_out, int out_size, void* d_ws, size_t ws_size,
                              hipStream_t stream) {
    const float* preds = (const float*)d_in[0];
    const float* targ  = (const float*)d_in[1];
    float* out = (float*)d_out;
    float* ch  = (float*)d_ws; // 2048 floats of per-group chamfer
    chamfer_kernel<<<NGROUP, 512, 0, stream>>>(preds, targ, ch);
    final_kernel<<<1, 256, 0, stream>>>(preds, targ, ch, out);
}

// Round 3
// 133.601 us; speedup vs baseline: 2.5312x; 2.5312x over previous
//
#include <hip/hip_runtime.h>
#include <hip/hip_bf16.h>

#define T_DIM 32772
#define NGROUP 2048

typedef short short8v __attribute__((ext_vector_type(8)));
typedef float float4v __attribute__((ext_vector_type(4)));
typedef unsigned int uint4v __attribute__((ext_vector_type(4)));

// packed f32x2 -> bf16x2 (RTNE) -> u32; compiler emits v_cvt_pk_bf16_f32
__device__ __forceinline__ unsigned int f2bf2(float a, float b) {
    __hip_bfloat162 h = __float22bfloat162_rn(make_float2(a, b));
    union { __hip_bfloat162 h; unsigned int u; } c; c.h = h;
    return c.u;
}

__device__ __forceinline__ short8v pack8(const float4v u0, const float4v u1) {
    uint4v p;
    p[0] = f2bf2(u0[0], u0[1]);
    p[1] = f2bf2(u0[2], u0[3]);
    p[2] = f2bf2(u1[0], u1[1]);
    p[3] = f2bf2(u1[2], u1[3]);
    return __builtin_bit_cast(short8v, p);
}

// One block per chamfer group g (B*H=2048), 8 waves.
// x = targ obs (n, 256x128): per-wave register A-frags (wave w owns rows 32w..32w+31).
// y = preds obs (m, 256x128): 4 chunks of 64 rows, double-buffered bf16 in LDS,
//     prefetched to registers one chunk ahead (loads overlap compute).
// P = x2[n] + y2[m] - 2*x.y ; loss1 = sum_m min_n P ; loss2 = sum_n min_m P
__global__ __launch_bounds__(512) void chamfer_kernel(
    const float* __restrict__ preds, const float* __restrict__ targ,
    float* __restrict__ ch_out)
{
    __shared__ __align__(16) unsigned short Ys[2][64 * 128]; // 2 x 16 KB swizzled bf16
    __shared__ float y2s[256];
    __shared__ float colmin_w[8][256];
    __shared__ float redA[8];
    __shared__ float redB[4];

    const int g = blockIdx.x;
    const float* gx = targ  + (size_t)g * T_DIM + 4;
    const float* gy = preds + (size_t)g * T_DIM + 4;

    const int tid  = threadIdx.x;
    const int lane = tid & 63;
    const int w    = tid >> 6;   // wave 0..7
    const int lg   = lane >> 4;  // k-quarter 0..3
    const int lc   = lane & 15;  // row/col within 16-tile

    // staging decomposition: 8 threads per y-row, 16 floats each
    const int prow = tid >> 3;   // row within chunk 0..63
    const int pcb  = tid & 7;    // 16-float column block 0..7
    char* Ysb = (char*)Ys;
    const int swz = (prow & 7) << 4;
    const int woff0 = prow * 256 + ((pcb * 32) ^ swz);

    // ---- prefetch y chunk 0 (issued before the long x-phase) ----
    float4v pf0, pf1, pf2, pf3;
    {
        const float* src = gy + (size_t)prow * 128 + pcb * 16;
        pf0 = *reinterpret_cast<const float4v*>(src);
        pf1 = *reinterpret_cast<const float4v*>(src + 4);
        pf2 = *reinterpret_cast<const float4v*>(src + 8);
        pf3 = *reinterpret_cast<const float4v*>(src + 12);
    }

    // ---- A fragments + x2, registers only ----
    short8v a_frag[2][4];
    float x2r[2][4];
    #pragma unroll
    for (int ti = 0; ti < 2; ++ti) {
        const float* xr = gx + (size_t)(w * 32 + ti * 16 + lc) * 128;
        float ss = 0.f;
        #pragma unroll
        for (int kk = 0; kk < 4; ++kk) {
            const float4v u0 = *reinterpret_cast<const float4v*>(xr + kk * 32 + lg * 8);
            const float4v u1 = *reinterpret_cast<const float4v*>(xr + kk * 32 + lg * 8 + 4);
            ss += u0[0]*u0[0] + u0[1]*u0[1] + u0[2]*u0[2] + u0[3]*u0[3];
            ss += u1[0]*u1[0] + u1[1]*u1[1] + u1[2]*u1[2] + u1[3]*u1[3];
            a_frag[ti][kk] = pack8(u0, u1);
        }
        ss += __shfl_xor(ss, 16);
        ss += __shfl_xor(ss, 32);
        #pragma unroll
        for (int r = 0; r < 4; ++r)
            x2r[ti][r] = __shfl(ss, lg * 4 + r);
    }

    // ---- write chunk 0 (y2 + swizzled bf16) ----
    {
        float ss = pf0[0]*pf0[0]+pf0[1]*pf0[1]+pf0[2]*pf0[2]+pf0[3]*pf0[3]
                 + pf1[0]*pf1[0]+pf1[1]*pf1[1]+pf1[2]*pf1[2]+pf1[3]*pf1[3]
                 + pf2[0]*pf2[0]+pf2[1]*pf2[1]+pf2[2]*pf2[2]+pf2[3]*pf2[3]
                 + pf3[0]*pf3[0]+pf3[1]*pf3[1]+pf3[2]*pf3[2]+pf3[3]*pf3[3];
        ss += __shfl_xor(ss, 1);
        ss += __shfl_xor(ss, 2);
        ss += __shfl_xor(ss, 4);
        if (pcb == 0) y2s[prow] = ss;
        *reinterpret_cast<short8v*>(Ysb + woff0)        = pack8(pf0, pf1);
        *reinterpret_cast<short8v*>(Ysb + (woff0 ^ 16)) = pack8(pf2, pf3);
    }
    __syncthreads();

    float rowmin[2][4];
    #pragma unroll
    for (int ti = 0; ti < 2; ++ti)
        #pragma unroll
        for (int r = 0; r < 4; ++r) rowmin[ti][r] = 1e30f;
    float cmin[4];

    // ---- 4 chunks, fully unrolled (static LDS buffer + cmin indices) ----
    #pragma unroll
    for (int c = 0; c < 4; ++c) {
        // issue next chunk's loads FIRST — they ride out the compute phase
        if (c < 3) {
            const float* src = gy + (size_t)((c + 1) * 64 + prow) * 128 + pcb * 16;
            pf0 = *reinterpret_cast<const float4v*>(src);
            pf1 = *reinterpret_cast<const float4v*>(src + 4);
            pf2 = *reinterpret_cast<const float4v*>(src + 8);
            pf3 = *reinterpret_cast<const float4v*>(src + 12);
        }

        // compute on chunk c from buffer c&1
        char* buf = Ysb + (c & 1) * 16384;
        #pragma unroll
        for (int tjl = 0; tjl < 4; ++tjl) {
            const int tj = c * 4 + tjl;
            short8v b_frag[4];
            #pragma unroll
            for (int kk = 0; kk < 4; ++kk) {
                const int addr = (tjl * 16 + lc) * 256 + ((kk * 64 + lg * 16) ^ ((lc & 7) << 4));
                b_frag[kk] = *reinterpret_cast<const short8v*>(buf + addr);
            }
            const float y2c = y2s[tj * 16 + lc];
            float cminv = 1e30f;
            #pragma unroll
            for (int ti = 0; ti < 2; ++ti) {
                float4v acc = {0.f, 0.f, 0.f, 0.f};
                #pragma unroll
                for (int kk = 0; kk < 4; ++kk)
                    acc = __builtin_amdgcn_mfma_f32_16x16x32_bf16(
                        a_frag[ti][kk], b_frag[kk], acc, 0, 0, 0);
                #pragma unroll
                for (int r = 0; r < 4; ++r) {
                    const float P = (x2r[ti][r] + y2c) - 2.0f * acc[r];
                    rowmin[ti][r] = fminf(rowmin[ti][r], P);
                    cminv = fminf(cminv, P);
                }
            }
            // full min over the wave's 32 rows, broadcast to all lg
            cminv = fminf(cminv, __shfl_xor(cminv, 16));
            cminv = fminf(cminv, __shfl_xor(cminv, 32));
            // lane (lg,lc) keeps col tj*16+lc when lg==tj&3  =>  cmin[c] is col c*64+lane
            if (lg == tjl) cmin[c] = cminv;
        }

        // write prefetched chunk c+1 into the other buffer (vmcnt waited here)
        if (c < 3) {
            float ss = pf0[0]*pf0[0]+pf0[1]*pf0[1]+pf0[2]*pf0[2]+pf0[3]*pf0[3]
                     + pf1[0]*pf1[0]+pf1[1]*pf1[1]+pf1[2]*pf1[2]+pf1[3]*pf1[3]
                     + pf2[0]*pf2[0]+pf2[1]*pf2[1]+pf2[2]*pf2[2]+pf2[3]*pf2[3]
                     + pf3[0]*pf3[0]+pf3[1]*pf3[1]+pf3[2]*pf3[2]+pf3[3]*pf3[3];
            ss += __shfl_xor(ss, 1);
            ss += __shfl_xor(ss, 2);
            ss += __shfl_xor(ss, 4);
            if (pcb == 0) y2s[(c + 1) * 64 + prow] = ss;
            char* wbuf = Ysb + ((c + 1) & 1) * 16384;
            *reinterpret_cast<short8v*>(wbuf + woff0)        = pack8(pf0, pf1);
            *reinterpret_cast<short8v*>(wbuf + (woff0 ^ 16)) = pack8(pf2, pf3);
            __syncthreads();
        }
    }

    // ---- per-wave col-mins -> LDS (once) ----
    #pragma unroll
    for (int s = 0; s < 4; ++s)
        colmin_w[w][s * 64 + lane] = cmin[s];

    // ---- loss2: row-mins (min over lc lanes, sum over rows) ----
    float s2 = 0.f;
    #pragma unroll
    for (int ti = 0; ti < 2; ++ti)
        #pragma unroll
        for (int r = 0; r < 4; ++r) {
            float v = rowmin[ti][r];
            v = fminf(v, __shfl_xor(v, 1));
            v = fminf(v, __shfl_xor(v, 2));
            v = fminf(v, __shfl_xor(v, 4));
            v = fminf(v, __shfl_xor(v, 8));
            s2 += v;
        }
    s2 += __shfl_xor(s2, 16);
    s2 += __shfl_xor(s2, 32);
    if (lane == 0) redA[w] = s2;
    __syncthreads();

    // ---- loss1: min over 8 waves per col, sum over 256 cols ----
    if (tid < 256) {
        float m = colmin_w[0][tid];
        #pragma unroll
        for (int ww = 1; ww < 8; ++ww) m = fminf(m, colmin_w[ww][tid]);
        #pragma unroll
        for (int s = 1; s < 64; s <<= 1) m += __shfl_xor(m, s);
        if (lane == 0) redB[w] = m;
    }
    __syncthreads();
    if (tid == 0) {
        const float l1 = redB[0] + redB[1] + redB[2] + redB[3];
        float l2 = 0.f;
        #pragma unroll
        for (int ww = 0; ww < 8; ++ww) l2 += redA[ww];
        ch_out[g] = l1 + l2;
    }
}

// Action loss + final reduction -> out[0], out[1]
__global__ __launch_bounds__(256) void final_kernel(
    const float* __restrict__ preds, const float* __restrict__ targ,
    const float* __restrict__ ch, float* __restrict__ out)
{
    __shared__ float rsw[4], rsa[4], rsc[4];
    const int tid = threadIdx.x;
    const int lane = tid & 63, w = tid >> 6;
    float sw = 0.f, sa0 = 0.f, sc = 0.f;
    for (int p = tid; p < NGROUP; p += 256) {
        const float* pp = preds + (size_t)p * T_DIM;
        const float* tt = targ  + (size_t)p * T_DIM;
        float al = 0.f;
        #pragma unroll
        for (int d = 0; d < 4; ++d) { const float df = pp[d] - tt[d]; al += df * df; }
        al *= 0.25f;
        if ((p & 31) == 0) { sw += 10.f * al; sa0 += al; }
        else               { sw += al; }
        sc += ch[p];
    }
    #pragma unroll
    for (int s = 1; s < 64; s <<= 1) {
        sw  += __shfl_xor(sw, s);
        sa0 += __shfl_xor(sa0, s);
        sc  += __shfl_xor(sc, s);
    }
    if (lane == 0) { rsw[w] = sw; rsa[w] = sa0; rsc[w] = sc; }
    __syncthreads();
    if (tid == 0) {
        float tsw = 0.f, tsa = 0.f, tsc = 0.f;
        #pragma unroll
        for (int i = 0; i < 4; ++i) { tsw += rsw[i]; tsa += rsa[i]; tsc += rsc[i]; }
        out[0] = tsw / 2048.f + tsc / 2048.f;
        out[1] = tsa / 64.f;
    }
}

extern "C" void kernel_launch(void* const* d_in, const int* in_sizes, int n_in,
                              void* d_out, int out_size, void* d_ws, size_t ws_size,
                              hipStream_t stream) {
    const float* preds = (const float*)d_in[0];
    const float* targ  = (const float*)d_in[1];
    float* out = (float*)d_out;
    float* ch  = (float*)d_ws; // 2048 floats of per-group chamfer
    chamfer_kernel<<<NGROUP, 512, 0, stream>>>(preds, targ, ch);
    final_kernel<<<1, 256, 0, stream>>>(preds, targ, ch, out);
}

// Round 4
// 128.299 us; speedup vs baseline: 2.6358x; 1.0413x over previous
//
#include <hip/hip_runtime.h>
#include <hip/hip_bf16.h>

#define T_DIM 32772
#define NGROUP 2048

typedef short short8v __attribute__((ext_vector_type(8)));
typedef float float4v __attribute__((ext_vector_type(4)));
typedef unsigned int uint4v __attribute__((ext_vector_type(4)));

// packed f32x2 -> bf16x2 (RTNE) -> u32; compiler emits v_cvt_pk_bf16_f32
__device__ __forceinline__ unsigned int f2bf2(float a, float b) {
    __hip_bfloat162 h = __float22bfloat162_rn(make_float2(a, b));
    union { __hip_bfloat162 h; unsigned int u; } c; c.h = h;
    return c.u;
}

__device__ __forceinline__ short8v pack8(const float4v u0, const float4v u1) {
    uint4v p;
    p[0] = f2bf2(u0[0], u0[1]);
    p[1] = f2bf2(u0[2], u0[3]);
    p[2] = f2bf2(u1[0], u1[1]);
    p[3] = f2bf2(u1[2], u1[3]);
    return __builtin_bit_cast(short8v, p);
}

// One block per chamfer group g (B*H=2048), 8 waves.
// x = targ obs (n, 256x128): per-wave register A-frags (wave w owns rows 32w..32w+31).
// y = preds obs (m, 256x128): 4 chunks of 64 rows, double-buffered bf16 in LDS,
//     prefetched to registers one chunk ahead (loads overlap compute).
// LDS layout (conflict-free add-rotate): 16B chunk c of row r at
//   r*256 + (((c&7)+r)&7)*16 + (c&8)*16   -> read slot = consecutive per lane.
// P = x2[n] + y2[m] - 2*x.y ; loss1 = sum_m min_n P ; loss2 = sum_n min_m P
__global__ __launch_bounds__(512) void chamfer_kernel(
    const float* __restrict__ preds, const float* __restrict__ targ,
    float* __restrict__ ch_out)
{
    __shared__ __align__(16) unsigned short Ys[2][64 * 128]; // 2 x 16 KB bf16
    __shared__ float y2s[256];
    __shared__ float colmin_w[8][256];
    __shared__ float redA[8];
    __shared__ float redB[4];

    const int g = blockIdx.x;
    const float* gx = targ  + (size_t)g * T_DIM + 4;
    const float* gy = preds + (size_t)g * T_DIM + 4;

    const int tid  = threadIdx.x;
    const int lane = tid & 63;
    const int w    = tid >> 6;   // wave 0..7
    const int lg   = lane >> 4;  // k-quarter 0..3
    const int lc   = lane & 15;  // row/col within 16-tile

    // staging decomposition: 8 threads per y-row; thread owns chunks pcb and pcb+8
    const int prow = tid >> 3;   // row within chunk 0..63
    const int pcb  = tid & 7;    // chunk pair selector 0..7
    char* Ysb = (char*)Ys;
    const int wslot = ((pcb + prow) & 7) << 4;
    const int woffA = prow * 256 + wslot;        // chunk pcb   (elems [pcb*8,+8))
    const int woffB = prow * 256 + 128 + wslot;  // chunk pcb+8 (elems [64+pcb*8,+8))

    // ---- prefetch y chunk 0 (issued before the long x-phase) ----
    float4v pf0, pf1, pf2, pf3;
    {
        const float* src = gy + (size_t)prow * 128 + pcb * 8;
        pf0 = *reinterpret_cast<const float4v*>(src);
        pf1 = *reinterpret_cast<const float4v*>(src + 4);
        pf2 = *reinterpret_cast<const float4v*>(src + 64);
        pf3 = *reinterpret_cast<const float4v*>(src + 68);
    }

    // ---- A fragments + x2, registers only ----
    short8v a_frag[2][4];
    float x2r[2][4];
    #pragma unroll
    for (int ti = 0; ti < 2; ++ti) {
        const float* xr = gx + (size_t)(w * 32 + ti * 16 + lc) * 128;
        float ss = 0.f;
        #pragma unroll
        for (int kk = 0; kk < 4; ++kk) {
            const float4v u0 = *reinterpret_cast<const float4v*>(xr + kk * 32 + lg * 8);
            const float4v u1 = *reinterpret_cast<const float4v*>(xr + kk * 32 + lg * 8 + 4);
            ss += u0[0]*u0[0] + u0[1]*u0[1] + u0[2]*u0[2] + u0[3]*u0[3];
            ss += u1[0]*u1[0] + u1[1]*u1[1] + u1[2]*u1[2] + u1[3]*u1[3];
            a_frag[ti][kk] = pack8(u0, u1);
        }
        ss += __shfl_xor(ss, 16);
        ss += __shfl_xor(ss, 32);
        #pragma unroll
        for (int r = 0; r < 4; ++r)
            x2r[ti][r] = __shfl(ss, lg * 4 + r);
    }

    // ---- write chunk 0 (y2 + add-rotate bf16) ----
    {
        float ss = pf0[0]*pf0[0]+pf0[1]*pf0[1]+pf0[2]*pf0[2]+pf0[3]*pf0[3]
                 + pf1[0]*pf1[0]+pf1[1]*pf1[1]+pf1[2]*pf1[2]+pf1[3]*pf1[3]
                 + pf2[0]*pf2[0]+pf2[1]*pf2[1]+pf2[2]*pf2[2]+pf2[3]*pf2[3]
                 + pf3[0]*pf3[0]+pf3[1]*pf3[1]+pf3[2]*pf3[2]+pf3[3]*pf3[3];
        ss += __shfl_xor(ss, 1);
        ss += __shfl_xor(ss, 2);
        ss += __shfl_xor(ss, 4);
        if (pcb == 0) y2s[prow] = ss;
        *reinterpret_cast<short8v*>(Ysb + woffA) = pack8(pf0, pf1);
        *reinterpret_cast<short8v*>(Ysb + woffB) = pack8(pf2, pf3);
    }
    __syncthreads();

    float rowmin[2][4];
    #pragma unroll
    for (int ti = 0; ti < 2; ++ti)
        #pragma unroll
        for (int r = 0; r < 4; ++r) rowmin[ti][r] = 1e30f;
    float cmin[4];

    // read slots (conflict-free): kk even -> (lg+lc)&7, kk odd -> (lg+lc+4)&7
    const int rs0 = ((lg + lc) & 7) << 4;
    const int rs1 = ((lg + lc + 4) & 7) << 4;

    // ---- 4 chunks, fully unrolled (static LDS buffer + cmin indices) ----
    #pragma unroll
    for (int c = 0; c < 4; ++c) {
        // issue next chunk's loads FIRST — they ride out the compute phase
        if (c < 3) {
            const float* src = gy + (size_t)((c + 1) * 64 + prow) * 128 + pcb * 8;
            pf0 = *reinterpret_cast<const float4v*>(src);
            pf1 = *reinterpret_cast<const float4v*>(src + 4);
            pf2 = *reinterpret_cast<const float4v*>(src + 64);
            pf3 = *reinterpret_cast<const float4v*>(src + 68);
        }

        // compute on chunk c from buffer c&1
        char* buf = Ysb + (c & 1) * 16384;
        #pragma unroll
        for (int tjl = 0; tjl < 4; ++tjl) {
            const int tj = c * 4 + tjl;
            const int rbyte = (tjl * 16 + lc) * 256;
            short8v b_frag[4];
            b_frag[0] = *reinterpret_cast<const short8v*>(buf + rbyte + rs0);
            b_frag[1] = *reinterpret_cast<const short8v*>(buf + rbyte + rs1);
            b_frag[2] = *reinterpret_cast<const short8v*>(buf + rbyte + 128 + rs0);
            b_frag[3] = *reinterpret_cast<const short8v*>(buf + rbyte + 128 + rs1);

            const float y2c = y2s[tj * 16 + lc];
            float cminv = 1e30f;
            #pragma unroll
            for (int ti = 0; ti < 2; ++ti) {
                float4v acc = {0.f, 0.f, 0.f, 0.f};
                #pragma unroll
                for (int kk = 0; kk < 4; ++kk)
                    acc = __builtin_amdgcn_mfma_f32_16x16x32_bf16(
                        a_frag[ti][kk], b_frag[kk], acc, 0, 0, 0);
                #pragma unroll
                for (int r = 0; r < 4; ++r) {
                    const float P = (x2r[ti][r] + y2c) - 2.0f * acc[r];
                    rowmin[ti][r] = fminf(rowmin[ti][r], P);
                    cminv = fminf(cminv, P);
                }
            }
            // full min over the wave's 32 rows, broadcast to all lg
            cminv = fminf(cminv, __shfl_xor(cminv, 16));
            cminv = fminf(cminv, __shfl_xor(cminv, 32));
            // lane (lg,lc) keeps col tj*16+lc when lg==tjl  =>  cmin[c] is col c*64+lane
            if (lg == tjl) cmin[c] = cminv;
        }

        // write prefetched chunk c+1 into the other buffer (vmcnt waited here)
        if (c < 3) {
            float ss = pf0[0]*pf0[0]+pf0[1]*pf0[1]+pf0[2]*pf0[2]+pf0[3]*pf0[3]
                     + pf1[0]*pf1[0]+pf1[1]*pf1[1]+pf1[2]*pf1[2]+pf1[3]*pf1[3]
                     + pf2[0]*pf2[0]+pf2[1]*pf2[1]+pf2[2]*pf2[2]+pf2[3]*pf2[3]
                     + pf3[0]*pf3[0]+pf3[1]*pf3[1]+pf3[2]*pf3[2]+pf3[3]*pf3[3];
            ss += __shfl_xor(ss, 1);
            ss += __shfl_xor(ss, 2);
            ss += __shfl_xor(ss, 4);
            if (pcb == 0) y2s[(c + 1) * 64 + prow] = ss;
            char* wbuf = Ysb + ((c + 1) & 1) * 16384;
            *reinterpret_cast<short8v*>(wbuf + woffA) = pack8(pf0, pf1);
            *reinterpret_cast<short8v*>(wbuf + woffB) = pack8(pf2, pf3);
            __syncthreads();
        }
    }

    // ---- per-wave col-mins -> LDS (once) ----
    #pragma unroll
    for (int s = 0; s < 4; ++s)
        colmin_w[w][s * 64 + lane] = cmin[s];

    // ---- loss2: row-mins (min over lc lanes, sum over rows) ----
    float s2 = 0.f;
    #pragma unroll
    for (int ti = 0; ti < 2; ++ti)
        #pragma unroll
        for (int r = 0; r < 4; ++r) {
            float v = rowmin[ti][r];
            v = fminf(v, __shfl_xor(v, 1));
            v = fminf(v, __shfl_xor(v, 2));
            v = fminf(v, __shfl_xor(v, 4));
            v = fminf(v, __shfl_xor(v, 8));
            s2 += v;
        }
    s2 += __shfl_xor(s2, 16);
    s2 += __shfl_xor(s2, 32);
    if (lane == 0) redA[w] = s2;
    __syncthreads();

    // ---- loss1: min over 8 waves per col, sum over 256 cols ----
    if (tid < 256) {
        float m = colmin_w[0][tid];
        #pragma unroll
        for (int ww = 1; ww < 8; ++ww) m = fminf(m, colmin_w[ww][tid]);
        #pragma unroll
        for (int s = 1; s < 64; s <<= 1) m += __shfl_xor(m, s);
        if (lane == 0) redB[w] = m;
    }
    __syncthreads();
    if (tid == 0) {
        const float l1 = redB[0] + redB[1] + redB[2] + redB[3];
        float l2 = 0.f;
        #pragma unroll
        for (int ww = 0; ww < 8; ++ww) l2 += redA[ww];
        ch_out[g] = l1 + l2;
    }
}

// Action loss + final reduction -> out[0], out[1]
__global__ __launch_bounds__(256) void final_kernel(
    const float* __restrict__ preds, const float* __restrict__ targ,
    const float* __restrict__ ch, float* __restrict__ out)
{
    __shared__ float rsw[4], rsa[4], rsc[4];
    const int tid = threadIdx.x;
    const int lane = tid & 63, w = tid >> 6;
    float sw = 0.f, sa0 = 0.f, sc = 0.f;
    for (int p = tid; p < NGROUP; p += 256) {
        const float* pp = preds + (size_t)p * T_DIM;
        const float* tt = targ  + (size_t)p * T_DIM;
        float al = 0.f;
        #pragma unroll
        for (int d = 0; d < 4; ++d) { const float df = pp[d] - tt[d]; al += df * df; }
        al *= 0.25f;
        if ((p & 31) == 0) { sw += 10.f * al; sa0 += al; }
        else               { sw += al; }
        sc += ch[p];
    }
    #pragma unroll
    for (int s = 1; s < 64; s <<= 1) {
        sw  += __shfl_xor(sw, s);
        sa0 += __shfl_xor(sa0, s);
        sc  += __shfl_xor(sc, s);
    }
    if (lane == 0) { rsw[w] = sw; rsa[w] = sa0; rsc[w] = sc; }
    __syncthreads();
    if (tid == 0) {
        float tsw = 0.f, tsa = 0.f, tsc = 0.f;
        #pragma unroll
        for (int i = 0; i < 4; ++i) { tsw += rsw[i]; tsa += rsa[i]; tsc += rsc[i]; }
        out[0] = tsw / 2048.f + tsc / 2048.f;
        out[1] = tsa / 64.f;
    }
}

extern "C" void kernel_launch(void* const* d_in, const int* in_sizes, int n_in,
                              void* d_out, int out_size, void* d_ws, size_t ws_size,
                              hipStream_t stream) {
    const float* preds = (const float*)d_in[0];
    const float* targ  = (const float*)d_in[1];
    float* out = (float*)d_out;
    float* ch  = (float*)d_ws; // 2048 floats of per-group chamfer
    chamfer_kernel<<<NGROUP, 512, 0, stream>>>(preds, targ, ch);
    final_kernel<<<1, 256, 0, stream>>>(preds, targ, ch, out);
}